// Round 17
// baseline (111.601 us; speedup 1.0000x reference)
//
#include <hip/hip_runtime.h>
#include <hip/hip_bf16.h>

#define B_  2
#define S_  2048
#define H_  1024
#define NH_ 16
#define HD_ 64
#define SMAX_ 12.0f   // fixed softmax max (exp2 domain); true score max ~3.6, f32 headroom ~2^100

typedef unsigned short u16;
typedef unsigned int   u32;
typedef __attribute__((ext_vector_type(4)))  float  f32x4;
typedef __attribute__((ext_vector_type(16))) float  f32x16;
typedef __attribute__((ext_vector_type(8)))  __bf16 bf16x8;
typedef __attribute__((ext_vector_type(4)))  unsigned int u32x4;
typedef __attribute__((ext_vector_type(4)))  unsigned short u16x4;

// f32 -> bf16 RNE (scalar)
__device__ __forceinline__ u16 f2bf(float f) {
  unsigned u = __builtin_bit_cast(unsigned, f);
  u += 0x7fffu + ((u >> 16) & 1u);
  return (u16)(u >> 16);
}
// packed f32x2 -> bf16x2 (one VALU op)
__device__ __forceinline__ u32 cvtpk(float lo, float hi) {
  u32 r;
  asm("v_cvt_pk_bf16_f32 %0, %1, %2" : "=v"(r) : "v"(lo), "v"(hi));
  return r;
}
// 2^x via v_exp_f32
__device__ __forceinline__ float ex2(float x) {
  float r;
  asm("v_exp_f32 %0, %1" : "=v"(r) : "v"(x));
  return r;
}

// async global->LDS, 16B per lane
__device__ __forceinline__ void gload_lds16(const void* g, void* l) {
  __builtin_amdgcn_global_load_lds(
      (const __attribute__((address_space(1))) void*)g,
      (__attribute__((address_space(3))) void*)l, 16, 0, 0);
}

// Fused f32->bf16 conversion of x + 4 weight matrices (one launch)
#define NX_ (4u * 1024u * 1024u)
__global__ __launch_bounds__(256) void cvt_all(const float* __restrict__ x,
                                               const float* __restrict__ w0, const float* __restrict__ w1,
                                               const float* __restrict__ w2, const float* __restrict__ w3,
                                               u16* __restrict__ xb,
                                               u16* __restrict__ o0, u16* __restrict__ o1,
                                               u16* __restrict__ o2, u16* __restrict__ o3) {
  size_t i4 = ((size_t)blockIdx.x * 256 + threadIdx.x) * 4;
  const float* src; u16* dst; size_t off;
  if (i4 < (size_t)NX_) { src = x; dst = xb; off = i4; }
  else {
    size_t j = i4 - NX_;
    int seg = (int)(j >> 20);
    off = j & ((1u << 20) - 1);
    src = seg == 0 ? w0 : seg == 1 ? w1 : seg == 2 ? w2 : w3;
    dst = seg == 0 ? o0 : seg == 1 ? o1 : seg == 2 ? o2 : o3;
  }
  float4 v = *reinterpret_cast<const float4*>(src + off);
  u16x4 o;
  o[0] = f2bf(v.x); o[1] = f2bf(v.y); o[2] = f2bf(v.z); o[3] = f2bf(v.w);
  *reinterpret_cast<u16x4*>(dst + off) = o;
}

__device__ __forceinline__ void store_out(float* C, size_t idx, float v) { C[idx] = v; }
__device__ __forceinline__ void store_out(u16* C, size_t idx, float v) { C[idx] = f2bf(v); }

// ---------------- GEMM core: BK=32 sub-buffers, TWO K-steps per barrier
// (stage both halves -> one vmcnt(0) drain -> one barrier pair -> 32 MFMA).
// Granule swizzle (R11): LDS[row][j] = global[row][j ^ m(row)],
// m(row) = (row&3)^((row>>2)&3); linear LDS dest + pre-swizzled source.
// lsA: 2*MI*1024 elems, lsB: 2*4096 elems.
template <int MI, typename OutT>
__device__ __forceinline__ void gemm_core(const u16* __restrict__ A, const u16* __restrict__ Bw,
                                          const float* __restrict__ bias, OutT* __restrict__ C,
                                          int M, int N, int K, float oscale, int m0, int n0,
                                          u16* lsA, u16* lsB) {
  const int t = threadIdx.x;
  const int w = t >> 6, lane = t & 63;
  const int g = lane >> 4, c = lane & 15;
  const int wr = w >> 1, wc = w & 1;

  f32x4 acc[MI][4] = {};
  const int rowS = w * 16 + (lane >> 2);
  const int sgr  = (lane & 3) ^ ((lane >> 2) & 3) ^ ((lane >> 4) & 3);
  const int colS = sgr * 8;                                   // elems
  const int rcol = (g ^ (c & 3) ^ ((c >> 2) & 3)) * 8;        // elems

  for (int k0 = 0; k0 < K; k0 += 64) {
    __syncthreads();
#pragma unroll
    for (int half = 0; half < 2; ++half) {
      const int kh0 = k0 + half * 32;
#pragma unroll
      for (int r = 0; r < MI / 2; ++r)
        gload_lds16(A + (size_t)(m0 + r * 64 + rowS) * K + kh0 + colS,
                    lsA + half * (MI * 1024) + r * 2048 + w * 512);
#pragma unroll
      for (int r = 0; r < 2; ++r)
        gload_lds16(Bw + (size_t)(n0 + r * 64 + rowS) * K + kh0 + colS,
                    lsB + half * 4096 + r * 2048 + w * 512);
    }
    asm volatile("s_waitcnt vmcnt(0)" ::: "memory");
    __syncthreads();

#pragma unroll
    for (int half = 0; half < 2; ++half) {
      const u16* la = lsA + half * (MI * 1024);
      const u16* lb = lsB + half * 4096;
      bf16x8 af[MI], bfr[4];
#pragma unroll
      for (int mi = 0; mi < MI; ++mi)
        af[mi] = *reinterpret_cast<const bf16x8*>(&la[(wr * (MI * 16) + mi * 16 + c) * 32 + rcol]);
#pragma unroll
      for (int ni = 0; ni < 4; ++ni)
        bfr[ni] = *reinterpret_cast<const bf16x8*>(&lb[(wc * 64 + ni * 16 + c) * 32 + rcol]);
#pragma unroll
      for (int mi = 0; mi < MI; ++mi)
#pragma unroll
        for (int ni = 0; ni < 4; ++ni)
          acc[mi][ni] = __builtin_amdgcn_mfma_f32_16x16x32_bf16(af[mi], bfr[ni], acc[mi][ni], 0, 0, 0);
    }
  }

#pragma unroll
  for (int mi = 0; mi < MI; ++mi) {
    int rowb = m0 + wr * (MI * 16) + mi * 16 + g * 4;
#pragma unroll
    for (int ni = 0; ni < 4; ++ni) {
      int col = n0 + wc * 64 + ni * 16 + c;
      float bv = bias[col];
#pragma unroll
      for (int r = 0; r < 4; ++r) {
        float v = (acc[mi][ni][r] + bv) * oscale;
        store_out(C, (size_t)(rowb + r) * N + col, v);
      }
    }
  }
}

// Fused QKV projection: MI=4, 1D grid 768, XCD-chunked
__global__ __launch_bounds__(256) void gemm_qkv(const u16* __restrict__ xb,
                                                const u16* __restrict__ Wq, const u16* __restrict__ Wk,
                                                const u16* __restrict__ Wv,
                                                const float* __restrict__ bq, const float* __restrict__ bk,
                                                const float* __restrict__ bv,
                                                u16* __restrict__ Q, u16* __restrict__ Kb, u16* __restrict__ Vb,
                                                int M, int K, float qscale) {
  __shared__ u16 lsA[2 * 4096];
  __shared__ u16 lsB[2 * 4096];
  const int fid = blockIdx.x;
  const int xcd = fid & 7, i = fid >> 3;        // i in 0..95
  const int mloc = i / 24, nn = i % 24;
  const int m0 = (xcd * 4 + mloc) * 128;
  const int ng = nn * 128;
  const int sel = ng >> 10, n0 = ng & 1023;
  const u16*  W    = sel == 0 ? Wq : sel == 1 ? Wk : Wv;
  const float* bia = sel == 0 ? bq : sel == 1 ? bk : bv;
  u16*        Cp   = sel == 0 ? Q  : sel == 1 ? Kb : Vb;
  float os = sel == 0 ? qscale : 1.0f;
  gemm_core<4, u16>(xb, W, bia, Cp, M, 1024, K, os, m0, n0, lsA, lsB);
}

// Output projection: 1D grid 512, XCD-chunked, BM=64
__global__ __launch_bounds__(256) void gemm_wo(const u16* __restrict__ A, const u16* __restrict__ Bw,
                                               const float* __restrict__ bias, float* __restrict__ C,
                                               int M, int N, int K) {
  __shared__ u16 lsA[2 * 2048];
  __shared__ u16 lsB[2 * 4096];
  const int fid = blockIdx.x;
  const int xcd = fid & 7, i = fid >> 3;        // 0..63
  const int mloc = i >> 3, nn = i & 7;
  const int m0 = (xcd * 8 + mloc) * 64;
  const int n0 = nn * 128;
  gemm_core<2, float>(A, Bw, bias, C, M, N, K, 1.0f, m0, n0, lsA, lsB);
}

// ---------------- Flash attention: causal, 32x32 MFMA, FIXED-MAX softmax,
// 2-phase pipeline (raw s_barrier + counted vmcnt), PAIRED q-tiles,
// P cross-half exchange via v_permlane32_swap_b32 (replaces 8 shfl + 24 sel).
// Grid 512: block = pair (31-j, j), 4 waves = 2 q-subtiles x 2 kv-parities.
// Q pre-scaled by log2(e)/8 (exp2 softmax).
__global__ __launch_bounds__(256, 4) void attn_fwd(const u16* __restrict__ Qg,
                                                   const u16* __restrict__ Kg,
                                                   const u16* __restrict__ Vg,
                                                   u16* __restrict__ Og) {
  __shared__ __align__(16) u16 smem[18432];   // 36864 B
  u16* lsKb = smem;                            // 4 K tiles  [32][64]
  u16* lsVb = smem + 8192;                     // 4 Vt tiles [64][40]
  float* lsO  = (float*)smem;                  // epilogue overlays
  float* lsML = (float*)((char*)smem + 20480);
  u16*   lsOT = smem + 10752;

  const int blk = blockIdx.x;                  // 512 blocks
  const int xcd = blk & 7, i = blk >> 3;       // i: 0..63
  const int pj = i & 15, bgrp = i >> 4;        // pair index, head group
  const int bh = xcd * 4 + bgrp;               // 4 whole (b,h) per XCD
  const int h = bh & 15, b = bh >> 4;

  const int t = threadIdx.x, w = t >> 6, lane = t & 63;
  const int c5 = lane & 31, hi = lane >> 5;
  const int sub = w & 1, par = w >> 1;
  const size_t headoff = (size_t)b * (S_ * H_) + (size_t)h * HD_;

  // staging maps: wave stages K and V of parity (w&1), rows half (w>>1)
  const int sp = w & 1, sh = w >> 1;
  const int kRowLoc = 16 * sh + (lane >> 3);
  const int kSrcCol = ((lane & 7) ^ (lane >> 3)) << 4;      // byte, pre-swizzled source
  const int vKvLoc  = 16 * sh + 2 * (lane >> 3);
  const int vD0     = 8 * (lane & 7);
  const int vKvx    = vKvLoc ^ (((lane & 7) & 3) << 3);     // swizzled kv column

  // hoisted per-lane LDS offsets
  int qkOff[4];
#pragma unroll
  for (int kc = 0; kc < 4; ++kc)
    qkOff[kc] = c5 * 128 + ((32 * kc + 16 * hi) ^ ((c5 & 7) << 4));
  const int pvRow0 = c5 * 80, pvRow1 = (32 + c5) * 80;      // bytes (stride 40 elems)
  int pvCol[2];
#pragma unroll
  for (int kp2 = 0; kp2 < 2; ++kp2)
    pvCol[kp2] = 2 * ((16 * kp2 + 8 * hi) ^ ((c5 >> 3) << 3));

  u32x4 vA, vB;
  auto STAGE = [&](int m) {
    const int kv0 = m * 64 + 32 * sp;
    const u16* vp = Vg + headoff + (size_t)(kv0 + vKvLoc) * H_ + vD0;
    vA = *reinterpret_cast<const u32x4*>(vp);        // 2 VMEM (V rows kv, kv+1)
    vB = *reinterpret_cast<const u32x4*>(vp + H_);
    char* kt = (char*)(lsKb + ((m & 1) * 2 + sp) * 2048) + 16 * sh * 128;
    const char* ks = (const char*)(Kg + headoff + (size_t)(kv0 + kRowLoc) * H_) + kSrcCol;
    gload_lds16(ks, kt);                              // 2 VMEM (K, 16 rows)
    gload_lds16(ks + 8 * (H_ * 2), kt + 8 * 128);
  };
  auto WRITEVT = [&](int m) {
    u16* vt = lsVb + ((m & 1) * 2 + sp) * 2560;
#pragma unroll
    for (int jj = 0; jj < 4; ++jj) {
      u32 lo  = __builtin_amdgcn_perm(vB[jj], vA[jj], 0x05040100u);
      u32 hi2 = __builtin_amdgcn_perm(vB[jj], vA[jj], 0x07060302u);
      *reinterpret_cast<u32*>(vt + (vD0 + 2 * jj) * 40 + vKvx)     = lo;
      *reinterpret_cast<u32*>(vt + (vD0 + 2 * jj + 1) * 40 + vKvx) = hi2;
    }
  };

  for (int seg = 0; seg < 2; ++seg) {
    const int qt = seg ? pj : 31 - pj;               // heavy tile first
    const int q0w = qt * 64 + 32 * sub;
    if (seg) __syncthreads();                        // protect smem overlays

    // Q B-frags: q = c5, d = 16kc + 8hi + j
    bf16x8 aq[4];
#pragma unroll
    for (int kc = 0; kc < 4; ++kc)
      aq[kc] = *reinterpret_cast<const bf16x8*>(Qg + headoff + (size_t)(q0w + c5) * H_ + kc * 16 + hi * 8);

    f32x16 o0 = {}, o1 = {};
    float lrun = 0.f;                                // in-lane partial row-sum

    // prologue: window 0
    STAGE(0);
    asm volatile("s_waitcnt vmcnt(2)" ::: "memory"); // V regs ready
    WRITEVT(0);
    asm volatile("s_waitcnt lgkmcnt(0)" ::: "memory");
    asm volatile("s_waitcnt vmcnt(0)" ::: "memory"); // K(0) in LDS
    __builtin_amdgcn_s_barrier();

    for (int n = 0; n <= qt; ++n) {
      const int buf = n & 1;
      const bool st = n < qt;
      if (st) STAGE(n + 1);                          // 4 VMEM in flight

      const bool live = (2 * n + par) <= (2 * qt + sub);
      const bool diag = (2 * n + par) == (2 * qt + sub);
      f32x16 sc = {};
      if (live) {
        const char* kb = (const char*)(lsKb + (buf * 2 + par) * 2048);
        __builtin_amdgcn_s_setprio(1);
#pragma unroll
        for (int kc = 0; kc < 4; ++kc) {
          bf16x8 ak = *reinterpret_cast<const bf16x8*>(kb + qkOff[kc]);
          sc = __builtin_amdgcn_mfma_f32_32x32x16_bf16(ak, aq[kc], sc, 0, 0, 0);
        }
        __builtin_amdgcn_s_setprio(0);
        if (diag) {
#pragma unroll
          for (int r = 0; r < 16; ++r) {
            int kvl = (r & 3) + 8 * (r >> 2) + 4 * hi;
            sc[r] = (kvl > c5) ? -1e30f : sc[r];
          }
        }
      }

      if (st) {                                      // async-STAGE split (T14)
        asm volatile("s_waitcnt vmcnt(2)" ::: "memory");
        WRITEVT(n + 1);
      }

      if (live) {
        const char* vtb = (const char*)(lsVb + (buf * 2 + par) * 2560);
        // fixed-max exp: p = 2^(sc - SMAX); masked entries -> 0
        float rs = 0.f;
        u32 wd0[2], wd1[2], wd2[2], wd3[2];
#pragma unroll
        for (int a = 0; a < 4; ++a) {
          float p0 = ex2(sc[4 * a + 0] - SMAX_), p1 = ex2(sc[4 * a + 1] - SMAX_);
          float p2 = ex2(sc[4 * a + 2] - SMAX_), p3 = ex2(sc[4 * a + 3] - SMAX_);
          rs += (p0 + p1) + (p2 + p3);
          u32* wdp = a == 0 ? wd0 : a == 1 ? wd1 : a == 2 ? wd2 : wd3;
          wdp[0] = cvtpk(p0, p1);
          wdp[1] = cvtpk(p2, p3);
        }
        lrun += rs;                                  // in-lane only; cross-half at end
        __builtin_amdgcn_s_setprio(1);
#pragma unroll
        for (int kp2 = 0; kp2 < 2; ++kp2) {
          // cross-half exchange via permlane32_swap:
          // swap(A,B): A' = {A_lo, B_lo}, B' = {A_hi, B_hi}  (lane-exact match
          // to the previous shfl_xor+select construction)
          u32 A0 = kp2 ? wd2[0] : wd0[0], A1 = kp2 ? wd2[1] : wd0[1];
          u32 B0 = kp2 ? wd3[0] : wd1[0], B1 = kp2 ? wd3[1] : wd1[1];
          asm("v_permlane32_swap_b32 %0, %1" : "+v"(A0), "+v"(B0));
          asm("v_permlane32_swap_b32 %0, %1" : "+v"(A1), "+v"(B1));
          u32x4 pw = {A0, A1, B0, B1};
          bf16x8 pb = __builtin_bit_cast(bf16x8, pw);
          bf16x8 av0 = *reinterpret_cast<const bf16x8*>(vtb + pvRow0 + pvCol[kp2]);
          bf16x8 av1 = *reinterpret_cast<const bf16x8*>(vtb + pvRow1 + pvCol[kp2]);
          o0 = __builtin_amdgcn_mfma_f32_32x32x16_bf16(av0, pb, o0, 0, 0, 0);
          o1 = __builtin_amdgcn_mfma_f32_32x32x16_bf16(av1, pb, o1, 0, 0, 0);
        }
        __builtin_amdgcn_s_setprio(0);
      }

      asm volatile("s_waitcnt lgkmcnt(0)" ::: "memory");       // Vt(n+1) writes done
      if (st) asm volatile("s_waitcnt vmcnt(0)" ::: "memory"); // K(n+1) in LDS
      __builtin_amdgcn_s_barrier();                            // raw barrier -- no drain
    }

    // finish the row-sum: one cross-half reduce after the whole loop
    lrun += (float)__shfl_xor(lrun, 32);

    // ---- parity merge + output (par0 stores, par1 combines & writes).
    // Same fixed M on both parities -> combine is a plain add.
    if (par == 0) {
      if (hi == 0) lsML[sub * 32 + c5] = lrun;
#pragma unroll
      for (int dt = 0; dt < 2; ++dt) {
        float* dst = lsO + ((size_t)((sub * 2 + dt) * 64 + lane)) * 20;
        const f32x16& oo = dt ? o1 : o0;
#pragma unroll
        for (int k4 = 0; k4 < 4; ++k4) {
          f32x4 v4 = {oo[4 * k4], oo[4 * k4 + 1], oo[4 * k4 + 2], oo[4 * k4 + 3]};
          *reinterpret_cast<f32x4*>(dst + 4 * k4) = v4;
        }
      }
    }
    __syncthreads();
    if (par == 1) {
      float lA = lsML[sub * 32 + c5];
      float linv = 1.0f / (lA + lrun);
      u16* ot = lsOT + sub * 2304;
#pragma unroll
      for (int dt = 0; dt < 2; ++dt) {
        const float* sp2 = lsO + ((size_t)((sub * 2 + dt) * 64 + lane)) * 20;
        f32x4 a4[4];
#pragma unroll
        for (int k4 = 0; k4 < 4; ++k4) a4[k4] = *reinterpret_cast<const f32x4*>(sp2 + 4 * k4);
        const f32x16& oo = dt ? o1 : o0;
#pragma unroll
        for (int a = 0; a < 4; ++a)
#pragma unroll
          for (int u = 0; u < 2; ++u) {
            int r = 4 * a + 2 * u;
            float e0 = (a4[a][2 * u]     + oo[r])     * linv;
            float e1 = (a4[a][2 * u + 1] + oo[r + 1]) * linv;
            int d = 32 * dt + 8 * a + 4 * hi + 2 * u;
            *reinterpret_cast<u32*>(ot + c5 * 72 + d) = cvtpk(e0, e1);
          }
      }
      asm volatile("s_waitcnt lgkmcnt(0)" ::: "memory");
      __builtin_amdgcn_sched_barrier(0);
#pragma unroll
      for (int rr = 0; rr < 4; ++rr) {
        int q = 8 * rr + (lane >> 3);
        int d8 = (lane & 7) * 8;
        u32x4 vv = *reinterpret_cast<const u32x4*>(lsOT + sub * 2304 + q * 72 + d8);
        *reinterpret_cast<u32x4*>(Og + headoff + (size_t)(qt * 64 + 32 * sub + q) * H_ + d8) = vv;
      }
    }
  }
}

extern "C" void kernel_launch(void* const* d_in, const int* in_sizes, int n_in,
                              void* d_out, int out_size, void* d_ws, size_t ws_size,
                              hipStream_t stream) {
  const float* x  = (const float*)d_in[0];
  const float* Wq = (const float*)d_in[1];
  const float* bq = (const float*)d_in[2];
  const float* Wk = (const float*)d_in[3];
  const float* bk = (const float*)d_in[4];
  const float* Wv = (const float*)d_in[5];
  const float* bv = (const float*)d_in[6];
  const float* Wo = (const float*)d_in[7];
  const float* bo = (const float*)d_in[8];
  float* out = (float*)d_out;

  const size_t MT = (size_t)B_ * S_;            // 4096
  char* p = (char*)d_ws;
  u16* xb  = (u16*)p; p += MT * H_ * 2;         // reused as ctx buffer after QKV
  u16* Wqb = (u16*)p; p += (size_t)H_ * H_ * 2;
  u16* Wkb = (u16*)p; p += (size_t)H_ * H_ * 2;
  u16* Wvb = (u16*)p; p += (size_t)H_ * H_ * 2;
  u16* Wob = (u16*)p; p += (size_t)H_ * H_ * 2;
  u16* Qb  = (u16*)p; p += MT * H_ * 2;
  u16* Kb  = (u16*)p; p += MT * H_ * 2;
  u16* Vb  = (u16*)p; p += MT * H_ * 2;
  u16* Cb  = xb;

  cvt_all<<<8192, 256, 0, stream>>>(x, Wq, Wk, Wv, Wo, xb, Wqb, Wkb, Wvb, Wob);

  const float qscale = 0.125f * 1.44269504088896f;  // log2(e)/sqrt(HD)
  gemm_qkv<<<768, 256, 0, stream>>>(xb, Wqb, Wkb, Wvb, bq, bk, bv,
                                    Qb, Kb, Vb, (int)MT, H_, qscale);

  attn_fwd<<<512, 256, 0, stream>>>(Qb, Kb, Vb, Cb);

  gemm_wo<<<512, 256, 0, stream>>>(Cb, Wob, bo, out, (int)MT, H_, H_);
}

// Round 18
// 104.141 us; speedup vs baseline: 1.0716x; 1.0716x over previous
//
#include <hip/hip_runtime.h>
#include <hip/hip_bf16.h>

#define B_  2
#define S_  2048
#define H_  1024
#define NH_ 16
#define HD_ 64
#define SMAX_ 12.0f   // fixed softmax max (exp2 domain); true score max ~3.6, f32 headroom ~2^100

typedef unsigned short u16;
typedef unsigned int   u32;
typedef __attribute__((ext_vector_type(4)))  float  f32x4;
typedef __attribute__((ext_vector_type(16))) float  f32x16;
typedef __attribute__((ext_vector_type(8)))  __bf16 bf16x8;
typedef __attribute__((ext_vector_type(4)))  unsigned int u32x4;
typedef __attribute__((ext_vector_type(4)))  unsigned short u16x4;

// f32 -> bf16 RNE (scalar)
__device__ __forceinline__ u16 f2bf(float f) {
  unsigned u = __builtin_bit_cast(unsigned, f);
  u += 0x7fffu + ((u >> 16) & 1u);
  return (u16)(u >> 16);
}
// packed f32x2 -> bf16x2 (one VALU op)
__device__ __forceinline__ u32 cvtpk(float lo, float hi) {
  u32 r;
  asm("v_cvt_pk_bf16_f32 %0, %1, %2" : "=v"(r) : "v"(lo), "v"(hi));
  return r;
}
// 2^x via v_exp_f32
__device__ __forceinline__ float ex2(float x) {
  float r;
  asm("v_exp_f32 %0, %1" : "=v"(r) : "v"(x));
  return r;
}

// async global->LDS, 16B per lane
__device__ __forceinline__ void gload_lds16(const void* g, void* l) {
  __builtin_amdgcn_global_load_lds(
      (const __attribute__((address_space(1))) void*)g,
      (__attribute__((address_space(3))) void*)l, 16, 0, 0);
}

// Fused f32->bf16 conversion of x + 4 weight matrices (one launch)
#define NX_ (4u * 1024u * 1024u)
__global__ __launch_bounds__(256) void cvt_all(const float* __restrict__ x,
                                               const float* __restrict__ w0, const float* __restrict__ w1,
                                               const float* __restrict__ w2, const float* __restrict__ w3,
                                               u16* __restrict__ xb,
                                               u16* __restrict__ o0, u16* __restrict__ o1,
                                               u16* __restrict__ o2, u16* __restrict__ o3) {
  size_t i4 = ((size_t)blockIdx.x * 256 + threadIdx.x) * 4;
  const float* src; u16* dst; size_t off;
  if (i4 < (size_t)NX_) { src = x; dst = xb; off = i4; }
  else {
    size_t j = i4 - NX_;
    int seg = (int)(j >> 20);
    off = j & ((1u << 20) - 1);
    src = seg == 0 ? w0 : seg == 1 ? w1 : seg == 2 ? w2 : w3;
    dst = seg == 0 ? o0 : seg == 1 ? o1 : seg == 2 ? o2 : o3;
  }
  float4 v = *reinterpret_cast<const float4*>(src + off);
  u16x4 o;
  o[0] = f2bf(v.x); o[1] = f2bf(v.y); o[2] = f2bf(v.z); o[3] = f2bf(v.w);
  *reinterpret_cast<u16x4*>(dst + off) = o;
}

__device__ __forceinline__ void store_out(float* C, size_t idx, float v) { C[idx] = v; }
__device__ __forceinline__ void store_out(u16* C, size_t idx, float v) { C[idx] = f2bf(v); }

// ---------------- GEMM core (R16 exact: R8 structure + granule swizzle):
// BK=32, 128-wide N tile, 4 waves 2x2, single K-step per barrier pair.
// LDS[row][j] = global[row][j ^ m(row)], m(row) = (row&3)^((row>>2)&3);
// linear LDS dest + pre-swizzled source (rule 21), XOR'd ds_read -> 2-way banks.
template <int MI, typename OutT>
__device__ __forceinline__ void gemm_core(const u16* __restrict__ A, const u16* __restrict__ Bw,
                                          const float* __restrict__ bias, OutT* __restrict__ C,
                                          int M, int N, int K, float oscale, int m0, int n0,
                                          u16* lsA, u16* lsB) {
  const int t = threadIdx.x;
  const int w = t >> 6, lane = t & 63;
  const int g = lane >> 4, c = lane & 15;
  const int wr = w >> 1, wc = w & 1;

  f32x4 acc[MI][4] = {};
  const int rowS = w * 16 + (lane >> 2);
  const int sgr  = (lane & 3) ^ ((lane >> 2) & 3) ^ ((lane >> 4) & 3);
  const int colS = sgr * 8;                                   // elems
  const int rcol = (g ^ (c & 3) ^ ((c >> 2) & 3)) * 8;        // elems

  for (int k0 = 0; k0 < K; k0 += 32) {
    __syncthreads();
#pragma unroll
    for (int r = 0; r < MI / 2; ++r)
      gload_lds16(A + (size_t)(m0 + r * 64 + rowS) * K + k0 + colS, lsA + r * 2048 + w * 512);
#pragma unroll
    for (int r = 0; r < 2; ++r)
      gload_lds16(Bw + (size_t)(n0 + r * 64 + rowS) * K + k0 + colS, lsB + r * 2048 + w * 512);
    asm volatile("s_waitcnt vmcnt(0)" ::: "memory");
    __syncthreads();

    bf16x8 af[MI], bfr[4];
#pragma unroll
    for (int mi = 0; mi < MI; ++mi)
      af[mi] = *reinterpret_cast<const bf16x8*>(&lsA[(wr * (MI * 16) + mi * 16 + c) * 32 + rcol]);
#pragma unroll
    for (int ni = 0; ni < 4; ++ni)
      bfr[ni] = *reinterpret_cast<const bf16x8*>(&lsB[(wc * 64 + ni * 16 + c) * 32 + rcol]);
#pragma unroll
    for (int mi = 0; mi < MI; ++mi)
#pragma unroll
      for (int ni = 0; ni < 4; ++ni)
        acc[mi][ni] = __builtin_amdgcn_mfma_f32_16x16x32_bf16(af[mi], bfr[ni], acc[mi][ni], 0, 0, 0);
  }

#pragma unroll
  for (int mi = 0; mi < MI; ++mi) {
    int rowb = m0 + wr * (MI * 16) + mi * 16 + g * 4;
#pragma unroll
    for (int ni = 0; ni < 4; ++ni) {
      int col = n0 + wc * 64 + ni * 16 + c;
      float bv = bias[col];
#pragma unroll
      for (int r = 0; r < 4; ++r) {
        float v = (acc[mi][ni][r] + bv) * oscale;
        store_out(C, (size_t)(rowb + r) * N + col, v);
      }
    }
  }
}

// Fused QKV projection: MI=4, 1D grid 768, XCD-chunked
__global__ __launch_bounds__(256) void gemm_qkv(const u16* __restrict__ xb,
                                                const u16* __restrict__ Wq, const u16* __restrict__ Wk,
                                                const u16* __restrict__ Wv,
                                                const float* __restrict__ bq, const float* __restrict__ bk,
                                                const float* __restrict__ bv,
                                                u16* __restrict__ Q, u16* __restrict__ Kb, u16* __restrict__ Vb,
                                                int M, int K, float qscale) {
  __shared__ u16 lsA[4096];
  __shared__ u16 lsB[4096];
  const int fid = blockIdx.x;
  const int xcd = fid & 7, i = fid >> 3;        // i in 0..95
  const int mloc = i / 24, nn = i % 24;
  const int m0 = (xcd * 4 + mloc) * 128;
  const int ng = nn * 128;
  const int sel = ng >> 10, n0 = ng & 1023;
  const u16*  W    = sel == 0 ? Wq : sel == 1 ? Wk : Wv;
  const float* bia = sel == 0 ? bq : sel == 1 ? bk : bv;
  u16*        Cp   = sel == 0 ? Q  : sel == 1 ? Kb : Vb;
  float os = sel == 0 ? qscale : 1.0f;
  gemm_core<4, u16>(xb, W, bia, Cp, M, 1024, K, os, m0, n0, lsA, lsB);
}

// Output projection: 1D grid 512, XCD-chunked, BM=64
__global__ __launch_bounds__(256) void gemm_wo(const u16* __restrict__ A, const u16* __restrict__ Bw,
                                               const float* __restrict__ bias, float* __restrict__ C,
                                               int M, int N, int K) {
  __shared__ u16 lsA[2048];
  __shared__ u16 lsB[4096];
  const int fid = blockIdx.x;
  const int xcd = fid & 7, i = fid >> 3;        // 0..63
  const int mloc = i >> 3, nn = i & 7;
  const int m0 = (xcd * 8 + mloc) * 64;
  const int n0 = nn * 128;
  gemm_core<2, float>(A, Bw, bias, C, M, N, K, 1.0f, m0, n0, lsA, lsB);
}

// ---------------- Flash attention (R17, kept): causal, 32x32 MFMA, FIXED-MAX
// softmax, 2-phase pipeline (raw s_barrier + counted vmcnt), PAIRED q-tiles,
// P cross-half exchange via v_permlane32_swap_b32.
// Grid 512: block = pair (31-j, j), 4 waves = 2 q-subtiles x 2 kv-parities.
// Q pre-scaled by log2(e)/8 (exp2 softmax).
__global__ __launch_bounds__(256, 4) void attn_fwd(const u16* __restrict__ Qg,
                                                   const u16* __restrict__ Kg,
                                                   const u16* __restrict__ Vg,
                                                   u16* __restrict__ Og) {
  __shared__ __align__(16) u16 smem[18432];   // 36864 B
  u16* lsKb = smem;                            // 4 K tiles  [32][64]
  u16* lsVb = smem + 8192;                     // 4 Vt tiles [64][40]
  float* lsO  = (float*)smem;                  // epilogue overlays
  float* lsML = (float*)((char*)smem + 20480);
  u16*   lsOT = smem + 10752;

  const int blk = blockIdx.x;                  // 512 blocks
  const int xcd = blk & 7, i = blk >> 3;       // i: 0..63
  const int pj = i & 15, bgrp = i >> 4;        // pair index, head group
  const int bh = xcd * 4 + bgrp;               // 4 whole (b,h) per XCD
  const int h = bh & 15, b = bh >> 4;

  const int t = threadIdx.x, w = t >> 6, lane = t & 63;
  const int c5 = lane & 31, hi = lane >> 5;
  const int sub = w & 1, par = w >> 1;
  const size_t headoff = (size_t)b * (S_ * H_) + (size_t)h * HD_;

  // staging maps: wave stages K and V of parity (w&1), rows half (w>>1)
  const int sp = w & 1, sh = w >> 1;
  const int kRowLoc = 16 * sh + (lane >> 3);
  const int kSrcCol = ((lane & 7) ^ (lane >> 3)) << 4;      // byte, pre-swizzled source
  const int vKvLoc  = 16 * sh + 2 * (lane >> 3);
  const int vD0     = 8 * (lane & 7);
  const int vKvx    = vKvLoc ^ (((lane & 7) & 3) << 3);     // swizzled kv column

  // hoisted per-lane LDS offsets
  int qkOff[4];
#pragma unroll
  for (int kc = 0; kc < 4; ++kc)
    qkOff[kc] = c5 * 128 + ((32 * kc + 16 * hi) ^ ((c5 & 7) << 4));
  const int pvRow0 = c5 * 80, pvRow1 = (32 + c5) * 80;      // bytes (stride 40 elems)
  int pvCol[2];
#pragma unroll
  for (int kp2 = 0; kp2 < 2; ++kp2)
    pvCol[kp2] = 2 * ((16 * kp2 + 8 * hi) ^ ((c5 >> 3) << 3));

  u32x4 vA, vB;
  auto STAGE = [&](int m) {
    const int kv0 = m * 64 + 32 * sp;
    const u16* vp = Vg + headoff + (size_t)(kv0 + vKvLoc) * H_ + vD0;
    vA = *reinterpret_cast<const u32x4*>(vp);        // 2 VMEM (V rows kv, kv+1)
    vB = *reinterpret_cast<const u32x4*>(vp + H_);
    char* kt = (char*)(lsKb + ((m & 1) * 2 + sp) * 2048) + 16 * sh * 128;
    const char* ks = (const char*)(Kg + headoff + (size_t)(kv0 + kRowLoc) * H_) + kSrcCol;
    gload_lds16(ks, kt);                              // 2 VMEM (K, 16 rows)
    gload_lds16(ks + 8 * (H_ * 2), kt + 8 * 128);
  };
  auto WRITEVT = [&](int m) {
    u16* vt = lsVb + ((m & 1) * 2 + sp) * 2560;
#pragma unroll
    for (int jj = 0; jj < 4; ++jj) {
      u32 lo  = __builtin_amdgcn_perm(vB[jj], vA[jj], 0x05040100u);
      u32 hi2 = __builtin_amdgcn_perm(vB[jj], vA[jj], 0x07060302u);
      *reinterpret_cast<u32*>(vt + (vD0 + 2 * jj) * 40 + vKvx)     = lo;
      *reinterpret_cast<u32*>(vt + (vD0 + 2 * jj + 1) * 40 + vKvx) = hi2;
    }
  };

  for (int seg = 0; seg < 2; ++seg) {
    const int qt = seg ? pj : 31 - pj;               // heavy tile first
    const int q0w = qt * 64 + 32 * sub;
    if (seg) __syncthreads();                        // protect smem overlays

    // Q B-frags: q = c5, d = 16kc + 8hi + j
    bf16x8 aq[4];
#pragma unroll
    for (int kc = 0; kc < 4; ++kc)
      aq[kc] = *reinterpret_cast<const bf16x8*>(Qg + headoff + (size_t)(q0w + c5) * H_ + kc * 16 + hi * 8);

    f32x16 o0 = {}, o1 = {};
    float lrun = 0.f;                                // in-lane partial row-sum

    // prologue: window 0
    STAGE(0);
    asm volatile("s_waitcnt vmcnt(2)" ::: "memory"); // V regs ready
    WRITEVT(0);
    asm volatile("s_waitcnt lgkmcnt(0)" ::: "memory");
    asm volatile("s_waitcnt vmcnt(0)" ::: "memory"); // K(0) in LDS
    __builtin_amdgcn_s_barrier();

    for (int n = 0; n <= qt; ++n) {
      const int buf = n & 1;
      const bool st = n < qt;
      if (st) STAGE(n + 1);                          // 4 VMEM in flight

      const bool live = (2 * n + par) <= (2 * qt + sub);
      const bool diag = (2 * n + par) == (2 * qt + sub);
      f32x16 sc = {};
      if (live) {
        const char* kb = (const char*)(lsKb + (buf * 2 + par) * 2048);
        __builtin_amdgcn_s_setprio(1);
#pragma unroll
        for (int kc = 0; kc < 4; ++kc) {
          bf16x8 ak = *reinterpret_cast<const bf16x8*>(kb + qkOff[kc]);
          sc = __builtin_amdgcn_mfma_f32_32x32x16_bf16(ak, aq[kc], sc, 0, 0, 0);
        }
        __builtin_amdgcn_s_setprio(0);
        if (diag) {
#pragma unroll
          for (int r = 0; r < 16; ++r) {
            int kvl = (r & 3) + 8 * (r >> 2) + 4 * hi;
            sc[r] = (kvl > c5) ? -1e30f : sc[r];
          }
        }
      }

      if (st) {                                      // async-STAGE split (T14)
        asm volatile("s_waitcnt vmcnt(2)" ::: "memory");
        WRITEVT(n + 1);
      }

      if (live) {
        const char* vtb = (const char*)(lsVb + (buf * 2 + par) * 2560);
        // fixed-max exp: p = 2^(sc - SMAX); masked entries -> 0
        float rs = 0.f;
        u32 wd0[2], wd1[2], wd2[2], wd3[2];
#pragma unroll
        for (int a = 0; a < 4; ++a) {
          float p0 = ex2(sc[4 * a + 0] - SMAX_), p1 = ex2(sc[4 * a + 1] - SMAX_);
          float p2 = ex2(sc[4 * a + 2] - SMAX_), p3 = ex2(sc[4 * a + 3] - SMAX_);
          rs += (p0 + p1) + (p2 + p3);
          u32* wdp = a == 0 ? wd0 : a == 1 ? wd1 : a == 2 ? wd2 : wd3;
          wdp[0] = cvtpk(p0, p1);
          wdp[1] = cvtpk(p2, p3);
        }
        lrun += rs;                                  // in-lane only; cross-half at end
        __builtin_amdgcn_s_setprio(1);
#pragma unroll
        for (int kp2 = 0; kp2 < 2; ++kp2) {
          // cross-half exchange via permlane32_swap:
          // swap(A,B): A' = {A_lo, B_lo}, B' = {A_hi, B_hi}
          u32 A0 = kp2 ? wd2[0] : wd0[0], A1 = kp2 ? wd2[1] : wd0[1];
          u32 B0 = kp2 ? wd3[0] : wd1[0], B1 = kp2 ? wd3[1] : wd1[1];
          asm("v_permlane32_swap_b32 %0, %1" : "+v"(A0), "+v"(B0));
          asm("v_permlane32_swap_b32 %0, %1" : "+v"(A1), "+v"(B1));
          u32x4 pw = {A0, A1, B0, B1};
          bf16x8 pb = __builtin_bit_cast(bf16x8, pw);
          bf16x8 av0 = *reinterpret_cast<const bf16x8*>(vtb + pvRow0 + pvCol[kp2]);
          bf16x8 av1 = *reinterpret_cast<const bf16x8*>(vtb + pvRow1 + pvCol[kp2]);
          o0 = __builtin_amdgcn_mfma_f32_32x32x16_bf16(av0, pb, o0, 0, 0, 0);
          o1 = __builtin_amdgcn_mfma_f32_32x32x16_bf16(av1, pb, o1, 0, 0, 0);
        }
        __builtin_amdgcn_s_setprio(0);
      }

      asm volatile("s_waitcnt lgkmcnt(0)" ::: "memory");       // Vt(n+1) writes done
      if (st) asm volatile("s_waitcnt vmcnt(0)" ::: "memory"); // K(n+1) in LDS
      __builtin_amdgcn_s_barrier();                            // raw barrier -- no drain
    }

    // finish the row-sum: one cross-half reduce after the whole loop
    lrun += (float)__shfl_xor(lrun, 32);

    // ---- parity merge + output (par0 stores, par1 combines & writes).
    // Same fixed M on both parities -> combine is a plain add.
    if (par == 0) {
      if (hi == 0) lsML[sub * 32 + c5] = lrun;
#pragma unroll
      for (int dt = 0; dt < 2; ++dt) {
        float* dst = lsO + ((size_t)((sub * 2 + dt) * 64 + lane)) * 20;
        const f32x16& oo = dt ? o1 : o0;
#pragma unroll
        for (int k4 = 0; k4 < 4; ++k4) {
          f32x4 v4 = {oo[4 * k4], oo[4 * k4 + 1], oo[4 * k4 + 2], oo[4 * k4 + 3]};
          *reinterpret_cast<f32x4*>(dst + 4 * k4) = v4;
        }
      }
    }
    __syncthreads();
    if (par == 1) {
      float lA = lsML[sub * 32 + c5];
      float linv = 1.0f / (lA + lrun);
      u16* ot = lsOT + sub * 2304;
#pragma unroll
      for (int dt = 0; dt < 2; ++dt) {
        const float* sp2 = lsO + ((size_t)((sub * 2 + dt) * 64 + lane)) * 20;
        f32x4 a4[4];
#pragma unroll
        for (int k4 = 0; k4 < 4; ++k4) a4[k4] = *reinterpret_cast<const f32x4*>(sp2 + 4 * k4);
        const f32x16& oo = dt ? o1 : o0;
#pragma unroll
        for (int a = 0; a < 4; ++a)
#pragma unroll
          for (int u = 0; u < 2; ++u) {
            int r = 4 * a + 2 * u;
            float e0 = (a4[a][2 * u]     + oo[r])     * linv;
            float e1 = (a4[a][2 * u + 1] + oo[r + 1]) * linv;
            int d = 32 * dt + 8 * a + 4 * hi + 2 * u;
            *reinterpret_cast<u32*>(ot + c5 * 72 + d) = cvtpk(e0, e1);
          }
      }
      asm volatile("s_waitcnt lgkmcnt(0)" ::: "memory");
      __builtin_amdgcn_sched_barrier(0);
#pragma unroll
      for (int rr = 0; rr < 4; ++rr) {
        int q = 8 * rr + (lane >> 3);
        int d8 = (lane & 7) * 8;
        u32x4 vv = *reinterpret_cast<const u32x4*>(lsOT + sub * 2304 + q * 72 + d8);
        *reinterpret_cast<u32x4*>(Og + headoff + (size_t)(qt * 64 + 32 * sub + q) * H_ + d8) = vv;
      }
    }
  }
}

extern "C" void kernel_launch(void* const* d_in, const int* in_sizes, int n_in,
                              void* d_out, int out_size, void* d_ws, size_t ws_size,
                              hipStream_t stream) {
  const float* x  = (const float*)d_in[0];
  const float* Wq = (const float*)d_in[1];
  const float* bq = (const float*)d_in[2];
  const float* Wk = (const float*)d_in[3];
  const float* bk = (const float*)d_in[4];
  const float* Wv = (const float*)d_in[5];
  const float* bv = (const float*)d_in[6];
  const float* Wo = (const float*)d_in[7];
  const float* bo = (const float*)d_in[8];
  float* out = (float*)d_out;

  const size_t MT = (size_t)B_ * S_;            // 4096
  char* p = (char*)d_ws;
  u16* xb  = (u16*)p; p += MT * H_ * 2;         // reused as ctx buffer after QKV
  u16* Wqb = (u16*)p; p += (size_t)H_ * H_ * 2;
  u16* Wkb = (u16*)p; p += (size_t)H_ * H_ * 2;
  u16* Wvb = (u16*)p; p += (size_t)H_ * H_ * 2;
  u16* Wob = (u16*)p; p += (size_t)H_ * H_ * 2;
  u16* Qb  = (u16*)p; p += MT * H_ * 2;
  u16* Kb  = (u16*)p; p += MT * H_ * 2;
  u16* Vb  = (u16*)p; p += MT * H_ * 2;
  u16* Cb  = xb;

  cvt_all<<<8192, 256, 0, stream>>>(x, Wq, Wk, Wv, Wo, xb, Wqb, Wkb, Wvb, Wob);

  const float qscale = 0.125f * 1.44269504088896f;  // log2(e)/sqrt(HD)
  gemm_qkv<<<768, 256, 0, stream>>>(xb, Wqb, Wkb, Wvb, bq, bk, bv,
                                    Qb, Kb, Vb, (int)MT, H_, qscale);

  attn_fwd<<<512, 256, 0, stream>>>(Qb, Kb, Vb, Cb);

  gemm_wo<<<512, 256, 0, stream>>>(Cb, Wob, bo, out, (int)MT, H_, H_);
}